// Round 5
// baseline (8754.572 us; speedup 1.0000x reference)
//
#include <hip/hip_runtime.h>
#include <hip/hip_bf16.h>
#include <stdint.h>

// ContainedLSTM: B=128, S=1024, I=256, H=256.
// Split-precision (Ootomo 2-term bf16) matmuls; LN folded into scalars.
// Recurrence: 16 blocks = 4 j-quarters x 4 group-pairs. Each block advances
// TWO independent batch-groups (gpair and gpair+4) per iteration so the two
// streams share every fabric round trip (one flag, one poll, one gather
// window) -- R4 showed the kernel is ~95% idle on agent-scope (coherence
// point) latency, ~4 round trips/step. W parked in AGPRs (shared by streams).

#define Bb 128
#define Ss 1024
#define Ii 256
#define Hh 256
#define G4v 1024
#define EPSF 1e-5f

typedef __bf16 bf16;
typedef __attribute__((ext_vector_type(8))) __bf16 bf16x8;
typedef __attribute__((ext_vector_type(4))) __bf16 bf16x4;
typedef __attribute__((ext_vector_type(4))) float f32x4;
typedef unsigned int u32;
typedef unsigned long long u64;

static __device__ __forceinline__ f32x4 mfma16(bf16x8 a, bf16x8 b, f32x4 c) {
  return __builtin_amdgcn_mfma_f32_16x16x32_bf16(a, b, c, 0, 0, 0);
}
static __device__ __forceinline__ float sigm(float x) { return 1.0f / (1.0f + __expf(-x)); }
static __device__ __forceinline__ float tanhf_(float x) {
  float e = __expf(-2.0f * fabsf(x));
  float t = (1.0f - e) / (1.0f + e);
  return x < 0.0f ? -t : t;
}
static __device__ __forceinline__ u32 packhl(float v) {
  bf16 h = (bf16)v;
  bf16 l = (bf16)(v - (float)h);
  return ((u32)__builtin_bit_cast(unsigned short, h) << 16) |
         (u32)__builtin_bit_cast(unsigned short, l);
}
static __device__ __forceinline__ bf16 bfu(unsigned short u) {
  return __builtin_bit_cast(bf16, u);
}

// ---------------- prep kernels ----------------
__global__ void k_conv_wih(const float* __restrict__ W, bf16* __restrict__ hi,
                           bf16* __restrict__ lo) {
  int i = (blockIdx.x * 256 + threadIdx.x) * 4;
  f32x4 v = *(const f32x4*)(W + i);
  bf16x4 h_, l_;
#pragma unroll
  for (int j = 0; j < 4; ++j) {
    bf16 hh = (bf16)v[j];
    h_[j] = hh;
    l_[j] = (bf16)(v[j] - (float)hh);
  }
  *(bf16x4*)(hi + i) = h_;
  *(bf16x4*)(lo + i) = l_;
}

// Wtil = W_hh * gamma, fragment-linear: Wf[(ntg*8+kt)*64 + lane][8] holds
// B-frag elem: Wtil[g = ntg*16 + (lane&15)][k = kt*32 + (lane>>4)*8 + j]
__global__ void k_prep_whh(const float* __restrict__ W, const float* __restrict__ gamma,
                           bf16* __restrict__ Whi, bf16* __restrict__ Wlo) {
  int tid = blockIdx.x * 256 + threadIdx.x;  // 0..32767
  int lane = tid & 63;
  int fk = tid >> 6;
  int ntg = fk >> 3, kt = fk & 7;
  int g = ntg * 16 + (lane & 15);
  int k = kt * 32 + ((lane >> 4) << 3);
  bf16x8 rh, rl;
#pragma unroll
  for (int j = 0; j < 8; ++j) {
    float wv = W[g * Hh + k + j] * gamma[k + j];
    bf16 hh = (bf16)wv;
    rh[j] = hh;
    rl[j] = (bf16)(wv - (float)hh);
  }
  *(bf16x8*)(Whi + (size_t)tid * 8) = rh;
  *(bf16x8*)(Wlo + (size_t)tid * 8) = rl;
}

__global__ void k_prep_rd(const float* __restrict__ W, const float* __restrict__ gamma,
                          const float* __restrict__ beta, const float* __restrict__ bih,
                          const float* __restrict__ bhh, float* __restrict__ RD) {
  int g = blockIdx.x * 256 + threadIdx.x;  // 1024 total
  float r = 0.f, d = 0.f;
  for (int k = 0; k < Hh; ++k) {
    float w = W[g * Hh + k];
    r += w * gamma[k];
    d += w * beta[k];
  }
  RD[2 * g] = r;
  RD[2 * g + 1] = d + bih[g] + bhh[g];
}

// ---------------- xw GEMM (split precision) ----------------
__global__ __launch_bounds__(256, 2) void k_gemm(const float* __restrict__ x,
                                                 const bf16* __restrict__ Whi,
                                                 const bf16* __restrict__ Wlo,
                                                 float* __restrict__ xw,
                                                 int t0, int Tc, int ntb) {
  __shared__ bf16 Bs[2][128 * 128];
  int bid = blockIdx.x;
  int b = bid & 127;
  int r2 = bid >> 7;
  int tb = r2 % ntb;
  int gt = r2 / ntb;
  int g0 = gt * 128;
  int tid = threadIdx.x, w = tid >> 6, lane = tid & 63;
  int li = lane & 15, lg = lane >> 4;
  char* BsB = (char*)Bs;
  int tbase = tb * 128 + 32 * w;
  f32x4 acc[2][8];
#pragma unroll
  for (int mt = 0; mt < 2; ++mt)
#pragma unroll
    for (int nt = 0; nt < 8; ++nt) acc[mt][nt] = (f32x4){0.f, 0.f, 0.f, 0.f};

  for (int kp = 0; kp < 2; ++kp) {
#pragma unroll
    for (int it = 0; it < 8; ++it) {
      int p = it * 4096 + tid * 16;
      int row = p >> 8, colb = p & 255;
      size_t goff = (size_t)(g0 + row) * 512 + kp * 256 + colb;
      int dst = row * 256 + (colb ^ ((row & 7) << 4));
      *(bf16x8*)(BsB + dst) = *(const bf16x8*)((const char*)Whi + goff);
      *(bf16x8*)(BsB + 32768 + dst) = *(const bf16x8*)((const char*)Wlo + goff);
    }
    __syncthreads();
#pragma unroll
    for (int kt = 0; kt < 4; ++kt) {
      int kl = kt * 32 + lg * 8;
      int kgl = kp * 128 + kl;
      bf16x8 ah[2], al[2];
#pragma unroll
      for (int mt = 0; mt < 2; ++mt) {
        int t = t0 + tbase + 16 * mt + li;
        const float* xp = x + ((size_t)b * Ss + t) * Ii + kgl;
        f32x4 f0 = *(const f32x4*)xp;
        f32x4 f1 = *(const f32x4*)(xp + 4);
        bf16x8 hv, lv;
#pragma unroll
        for (int j = 0; j < 4; ++j) {
          bf16 h0 = (bf16)f0[j];
          hv[j] = h0;
          lv[j] = (bf16)(f0[j] - (float)h0);
          bf16 h1 = (bf16)f1[j];
          hv[4 + j] = h1;
          lv[4 + j] = (bf16)(f1[j] - (float)h1);
        }
        ah[mt] = hv;
        al[mt] = lv;
      }
#pragma unroll
      for (int nt = 0; nt < 8; ++nt) {
        int grow = nt * 16 + li;
        int off = grow * 256 + ((kl * 2) ^ ((grow & 7) << 4));
        bf16x8 bh = *(const bf16x8*)(BsB + off);
        bf16x8 bl = *(const bf16x8*)(BsB + 32768 + off);
#pragma unroll
        for (int mt = 0; mt < 2; ++mt) {
          acc[mt][nt] = mfma16(ah[mt], bh, acc[mt][nt]);
          acc[mt][nt] = mfma16(ah[mt], bl, acc[mt][nt]);
          acc[mt][nt] = mfma16(al[mt], bh, acc[mt][nt]);
        }
      }
    }
    __syncthreads();
  }
#pragma unroll
  for (int mt = 0; mt < 2; ++mt)
#pragma unroll
    for (int nt = 0; nt < 8; ++nt)
#pragma unroll
      for (int r = 0; r < 4; ++r) {
        int tl = tbase + 16 * mt + lg * 4 + r;
        int g = g0 + nt * 16 + li;
        xw[((size_t)b * Tc + tl) * G4v + g] = acc[mt][nt][r];
      }
}

// ---------------- recurrence (dual-stream) ----------------
// grid: 16 blocks, bid = q*4 + gpair; block 256 thr / 4 waves.
// stream 0: batch-group gpair; stream 1: batch-group gpair+4.
__global__ __launch_bounds__(256, 1) void k_recur(
    const bf16* __restrict__ Whi_f, const bf16* __restrict__ Wlo_f,
    const float* __restrict__ xw, const int* __restrict__ mask,
    const float* __restrict__ RD, float* __restrict__ st_h, float* __restrict__ st_c,
    float* __restrict__ st_o, u32* pub_h, u64* pub_s, int* flags,
    float* __restrict__ out, int t0, int Tc, int first, int last) {
  __shared__ bf16 hbA[2][16 * 256];  // stream A h hi/lo planes (swizzled)
  __shared__ bf16 hbB[2][16 * 256];  // stream B
  __shared__ float mursA[16][2], mursB[16][2];
  __shared__ float2 spwA[4][16], spwB[4][16];  // per-wave row partials (s,ss)
  __shared__ float spart[16][16][2];           // init-path only
  int bid = blockIdx.x;
  int gpair = bid & 3, q = bid >> 2;
  int tid = threadIdx.x, w = tid >> 6, lane = tid & 63;
  int li = lane & 15, lg = lane >> 4;
  int b0A = gpair * 16, b0B = (gpair + 4) * 16;
  int jloc = (q * 4 + w) * 16 + li;
  char* hbAB = (char*)hbA;
  char* hbBB = (char*)hbB;

  // park this wave's W-quarter (hi+lo) in AGPRs (pin against remat/spill)
  bf16x8 wph[4][8], wpl[4][8];
#pragma unroll
  for (int c = 0; c < 4; ++c)
#pragma unroll
    for (int kt = 0; kt < 8; ++kt) {
      int ntg = c * 16 + q * 4 + w;
      size_t off = ((size_t)(ntg * 8 + kt) * 64 + lane) * 8;
      wph[c][kt] = *(const bf16x8*)(Whi_f + off);
      wpl[c][kt] = *(const bf16x8*)(Wlo_f + off);
      asm volatile("" : "+a"(wph[c][kt]), "+a"(wpl[c][kt]));
    }
  float Rr[4], Dd[4];
#pragma unroll
  for (int c = 0; c < 4; ++c) {
    int g = c * 256 + jloc;
    Rr[c] = RD[2 * g];
    Dd[c] = RD[2 * g + 1];
  }

  float cstA[4], ostA[4], cstB[4], ostB[4];
  if (first) {
#pragma unroll
    for (int i = 0; i < 16; ++i) {
      hbA[0][tid * 16 + i] = (bf16)0.0f;
      hbA[1][tid * 16 + i] = (bf16)0.0f;
      hbB[0][tid * 16 + i] = (bf16)0.0f;
      hbB[1][tid * 16 + i] = (bf16)0.0f;
    }
#pragma unroll
    for (int r = 0; r < 4; ++r) { cstA[r] = 0.f; ostA[r] = 0.f; cstB[r] = 0.f; ostB[r] = 0.f; }
    if (tid < 16) {
      mursA[tid][0] = 0.f; mursA[tid][1] = rsqrtf(EPSF);
      mursB[tid][0] = 0.f; mursB[tid][1] = rsqrtf(EPSF);
    }
  } else {
    int row = tid >> 4, cs = tid & 15, jseg = cs * 16;
    // pass A
    {
      float s = 0.f, ss = 0.f;
#pragma unroll
      for (int i = 0; i < 16; ++i) {
        float v = st_h[(size_t)(b0A + row) * Hh + jseg + i];
        s += v; ss += v * v;
        bf16 hh = (bf16)v;
        int boff = row * 512 + (((jseg + i) * 2) ^ ((row & 7) << 4));
        *(bf16*)(hbAB + boff) = hh;
        *(bf16*)(hbAB + 8192 + boff) = (bf16)(v - (float)hh);
      }
      spart[row][cs][0] = s;
      spart[row][cs][1] = ss;
#pragma unroll
      for (int r = 0; r < 4; ++r) {
        int m = lg * 4 + r;
        cstA[r] = st_c[(size_t)(b0A + m) * Hh + jloc];
        ostA[r] = st_o[(size_t)(b0A + m) * Hh + jloc];
      }
      __syncthreads();
      if (tid < 16) {
        float s2 = 0.f, ss2 = 0.f;
#pragma unroll
        for (int i = 0; i < 16; ++i) { s2 += spart[tid][i][0]; ss2 += spart[tid][i][1]; }
        float mu = s2 * (1.f / 256.f);
        float var = ss2 * (1.f / 256.f) - mu * mu;
        float rs = rsqrtf(var + EPSF);
        mursA[tid][0] = mu * rs;
        mursA[tid][1] = rs;
      }
      __syncthreads();
    }
    // pass B
    {
      float s = 0.f, ss = 0.f;
#pragma unroll
      for (int i = 0; i < 16; ++i) {
        float v = st_h[(size_t)(b0B + row) * Hh + jseg + i];
        s += v; ss += v * v;
        bf16 hh = (bf16)v;
        int boff = row * 512 + (((jseg + i) * 2) ^ ((row & 7) << 4));
        *(bf16*)(hbBB + boff) = hh;
        *(bf16*)(hbBB + 8192 + boff) = (bf16)(v - (float)hh);
      }
      spart[row][cs][0] = s;
      spart[row][cs][1] = ss;
#pragma unroll
      for (int r = 0; r < 4; ++r) {
        int m = lg * 4 + r;
        cstB[r] = st_c[(size_t)(b0B + m) * Hh + jloc];
        ostB[r] = st_o[(size_t)(b0B + m) * Hh + jloc];
      }
      __syncthreads();
      if (tid < 16) {
        float s2 = 0.f, ss2 = 0.f;
#pragma unroll
        for (int i = 0; i < 16; ++i) { s2 += spart[tid][i][0]; ss2 += spart[tid][i][1]; }
        float mu = s2 * (1.f / 256.f);
        float var = ss2 * (1.f / 256.f) - mu * mu;
        float rs = rsqrtf(var + EPSF);
        mursB[tid][0] = mu * rs;
        mursB[tid][1] = rs;
      }
    }
  }
  __syncthreads();

  // preload xw/mask for tl=0 (both streams)
  float xwvA[4][4], xwvB[4][4];
  int mkA[4], mkB[4];
#pragma unroll
  for (int c = 0; c < 4; ++c)
#pragma unroll
    for (int r = 0; r < 4; ++r) {
      xwvA[c][r] = xw[((size_t)(b0A + lg * 4 + r) * Tc + 0) * G4v + c * 256 + jloc];
      xwvB[c][r] = xw[((size_t)(b0B + lg * 4 + r) * Tc + 0) * G4v + c * 256 + jloc];
    }
#pragma unroll
  for (int r = 0; r < 4; ++r) {
    mkA[r] = mask[(size_t)(b0A + lg * 4 + r) * Ss + t0];
    mkB[r] = mask[(size_t)(b0B + lg * 4 + r) * Ss + t0];
  }

  for (int tl = 0; tl < Tc; ++tl) {
    int tg = t0 + tl;
    int slot = (tg + 1) & 1;
    float hnA[4], hnB[4];

    // ---- stream A: MFMA + gates + publish ----
    {
      f32x4 acc[4];
#pragma unroll
      for (int c = 0; c < 4; ++c) acc[c] = (f32x4){0.f, 0.f, 0.f, 0.f};
#pragma unroll
      for (int kt = 0; kt < 8; ++kt) {
        int aoff = li * 512 + (((kt * 32 + lg * 8) * 2) ^ ((li & 7) << 4));
        bf16x8 ah = *(const bf16x8*)(hbAB + aoff);
        bf16x8 al = *(const bf16x8*)(hbAB + 8192 + aoff);
#pragma unroll
        for (int c = 0; c < 4; ++c) {
          acc[c] = mfma16(ah, wph[c][kt], acc[c]);
          acc[c] = mfma16(ah, wpl[c][kt], acc[c]);
          acc[c] = mfma16(al, wph[c][kt], acc[c]);
        }
      }
#pragma unroll
      for (int r = 0; r < 4; ++r) {
        int m = lg * 4 + r;
        float mrs = mursA[m][0], rsv = mursA[m][1];
        float i_ = acc[0][r] * rsv - mrs * Rr[0] + Dd[0] + xwvA[0][r];
        float f_ = acc[1][r] * rsv - mrs * Rr[1] + Dd[1] + xwvA[1][r];
        float g_ = acc[2][r] * rsv - mrs * Rr[2] + Dd[2] + xwvA[2][r];
        float o_ = acc[3][r] * rsv - mrs * Rr[3] + Dd[3] + xwvA[3][r];
        float cn = sigm(f_) * cstA[r] + sigm(i_) * tanhf_(g_);
        float hn = sigm(o_) * tanhf_(cn);
        cstA[r] = cn;
        ostA[r] = mkA[r] ? ostA[r] : hn;
        hnA[r] = hn;
      }
      u32* ph = pub_h + ((size_t)(slot * 16 + bid) * 2 + 0) * 1024;
#pragma unroll
      for (int r = 0; r < 4; ++r)
        __hip_atomic_store(&ph[(lg * 4 + r) * 64 + w * 16 + li], packhl(hnA[r]),
                           __ATOMIC_RELAXED, __HIP_MEMORY_SCOPE_AGENT);
      float sr[4], qr[4];
#pragma unroll
      for (int r = 0; r < 4; ++r) { sr[r] = hnA[r]; qr[r] = hnA[r] * hnA[r]; }
#pragma unroll
      for (int msk = 1; msk < 16; msk <<= 1)
#pragma unroll
        for (int r = 0; r < 4; ++r) {
          sr[r] += __shfl_xor(sr[r], msk);
          qr[r] += __shfl_xor(qr[r], msk);
        }
      if (li == 0) {
        u64* ps = pub_s + ((size_t)(slot * 16 + bid) * 2 + 0) * 64;
#pragma unroll
        for (int r = 0; r < 4; ++r) {
          spwA[w][lg * 4 + r] = make_float2(sr[r], qr[r]);
          u64 pv = ((u64)__builtin_bit_cast(u32, qr[r]) << 32) |
                   (u64)__builtin_bit_cast(u32, sr[r]);
          __hip_atomic_store(&ps[w * 16 + lg * 4 + r], pv, __ATOMIC_RELAXED,
                             __HIP_MEMORY_SCOPE_AGENT);
        }
      }
    }

    // ---- stream B: MFMA + gates + publish (hides A's store drain) ----
    {
      f32x4 acc[4];
#pragma unroll
      for (int c = 0; c < 4; ++c) acc[c] = (f32x4){0.f, 0.f, 0.f, 0.f};
#pragma unroll
      for (int kt = 0; kt < 8; ++kt) {
        int aoff = li * 512 + (((kt * 32 + lg * 8) * 2) ^ ((li & 7) << 4));
        bf16x8 ah = *(const bf16x8*)(hbBB + aoff);
        bf16x8 al = *(const bf16x8*)(hbBB + 8192 + aoff);
#pragma unroll
        for (int c = 0; c < 4; ++c) {
          acc[c] = mfma16(ah, wph[c][kt], acc[c]);
          acc[c] = mfma16(ah, wpl[c][kt], acc[c]);
          acc[c] = mfma16(al, wph[c][kt], acc[c]);
        }
      }
#pragma unroll
      for (int r = 0; r < 4; ++r) {
        int m = lg * 4 + r;
        float mrs = mursB[m][0], rsv = mursB[m][1];
        float i_ = acc[0][r] * rsv - mrs * Rr[0] + Dd[0] + xwvB[0][r];
        float f_ = acc[1][r] * rsv - mrs * Rr[1] + Dd[1] + xwvB[1][r];
        float g_ = acc[2][r] * rsv - mrs * Rr[2] + Dd[2] + xwvB[2][r];
        float o_ = acc[3][r] * rsv - mrs * Rr[3] + Dd[3] + xwvB[3][r];
        float cn = sigm(f_) * cstB[r] + sigm(i_) * tanhf_(g_);
        float hn = sigm(o_) * tanhf_(cn);
        cstB[r] = cn;
        ostB[r] = mkB[r] ? ostB[r] : hn;
        hnB[r] = hn;
      }
      u32* ph = pub_h + ((size_t)(slot * 16 + bid) * 2 + 1) * 1024;
#pragma unroll
      for (int r = 0; r < 4; ++r)
        __hip_atomic_store(&ph[(lg * 4 + r) * 64 + w * 16 + li], packhl(hnB[r]),
                           __ATOMIC_RELAXED, __HIP_MEMORY_SCOPE_AGENT);
      float sr[4], qr[4];
#pragma unroll
      for (int r = 0; r < 4; ++r) { sr[r] = hnB[r]; qr[r] = hnB[r] * hnB[r]; }
#pragma unroll
      for (int msk = 1; msk < 16; msk <<= 1)
#pragma unroll
        for (int r = 0; r < 4; ++r) {
          sr[r] += __shfl_xor(sr[r], msk);
          qr[r] += __shfl_xor(qr[r], msk);
        }
      if (li == 0) {
        u64* ps = pub_s + ((size_t)(slot * 16 + bid) * 2 + 1) * 64;
#pragma unroll
        for (int r = 0; r < 4; ++r) {
          spwB[w][lg * 4 + r] = make_float2(sr[r], qr[r]);
          u64 pv = ((u64)__builtin_bit_cast(u32, qr[r]) << 32) |
                   (u64)__builtin_bit_cast(u32, sr[r]);
          __hip_atomic_store(&ps[w * 16 + lg * 4 + r], pv, __ATOMIC_RELAXED,
                             __HIP_MEMORY_SCOPE_AGENT);
        }
      }
    }

    if (tl == Tc - 1) {
#pragma unroll
      for (int r = 0; r < 4; ++r) {
        int m = lg * 4 + r;
        st_h[(size_t)(b0A + m) * Hh + jloc] = hnA[r];
        st_c[(size_t)(b0A + m) * Hh + jloc] = cstA[r];
        st_o[(size_t)(b0A + m) * Hh + jloc] = ostA[r];
        st_h[(size_t)(b0B + m) * Hh + jloc] = hnB[r];
        st_c[(size_t)(b0B + m) * Hh + jloc] = cstB[r];
        st_o[(size_t)(b0B + m) * Hh + jloc] = ostB[r];
      }
      if (last) {
#pragma unroll
        for (int r = 0; r < 4; ++r) {
          out[(size_t)(b0A + lg * 4 + r) * Hh + jloc] = ostA[r];
          out[(size_t)(b0B + lg * 4 + r) * Hh + jloc] = ostB[r];
        }
      }
    }

    // drain all publish stores, then issue next-step prefetch (overlaps sync)
    asm volatile("s_waitcnt vmcnt(0)" ::: "memory");
    {
      int tln = (tl + 1 < Tc) ? tl + 1 : Tc - 1;
#pragma unroll
      for (int c = 0; c < 4; ++c)
#pragma unroll
        for (int r = 0; r < 4; ++r) {
          xwvA[c][r] = xw[((size_t)(b0A + lg * 4 + r) * Tc + tln) * G4v + c * 256 + jloc];
          xwvB[c][r] = xw[((size_t)(b0B + lg * 4 + r) * Tc + tln) * G4v + c * 256 + jloc];
        }
#pragma unroll
      for (int r = 0; r < 4; ++r) {
        mkA[r] = mask[(size_t)(b0A + lg * 4 + r) * Ss + t0 + tln];
        mkB[r] = mask[(size_t)(b0B + lg * 4 + r) * Ss + t0 + tln];
      }
    }
    __syncthreads();  // SYNC_B: all waves' publishes drained
    if (tid == 0)
      __hip_atomic_store(&flags[bid], tg + 1, __ATOMIC_RELAXED, __HIP_MEMORY_SCOPE_AGENT);
    if (tid >= 1 && tid <= 3) {
      int qq = (q + tid) & 3;
      int pbid = qq * 4 + gpair;
      int cnt = 0;
      while (__hip_atomic_load(&flags[pbid], __ATOMIC_RELAXED, __HIP_MEMORY_SCOPE_AGENT) <
             tg + 1) {
        if (++cnt > (1 << 24)) break;  // hang insurance
      }
    }
    __syncthreads();  // SYNC_C: all partner data ready

    // ---- gather both streams' partner slices in one latency window ----
    {
      int grow = tid >> 4, gcg = tid & 15;
      u32 gv[3][2][4];
#pragma unroll
      for (int pi = 0; pi < 3; ++pi) {
        int qq = (q + 1 + pi) & 3;
        int pbid = qq * 4 + gpair;
#pragma unroll
        for (int s = 0; s < 2; ++s) {
          const u32* src = pub_h + ((size_t)(slot * 16 + pbid) * 2 + s) * 1024 +
                           grow * 64 + gcg * 4;
#pragma unroll
          for (int e = 0; e < 4; ++e)
            gv[pi][s][e] =
                __hip_atomic_load(&src[e], __ATOMIC_RELAXED, __HIP_MEMORY_SCOPE_AGENT);
        }
      }
#pragma unroll
      for (int pi = 0; pi < 3; ++pi) {
        int qq = (q + 1 + pi) & 3;
        int boff = grow * 512 + (((qq * 64 + gcg * 4) * 2) ^ ((grow & 7) << 4));
#pragma unroll
        for (int s = 0; s < 2; ++s) {
          bf16x4 h4, l4;
#pragma unroll
          for (int e = 0; e < 4; ++e) {
            h4[e] = bfu((unsigned short)(gv[pi][s][e] >> 16));
            l4[e] = bfu((unsigned short)(gv[pi][s][e] & 0xffffu));
          }
          char* hx = s ? hbBB : hbAB;
          *(bf16x4*)(hx + boff) = h4;
          *(bf16x4*)(hx + 8192 + boff) = l4;
        }
      }
      // own slices
#pragma unroll
      for (int r = 0; r < 4; ++r) {
        int m = lg * 4 + r;
        int boff = m * 512 + ((jloc * 2) ^ ((m & 7) << 4));
        float hn = hnA[r];
        bf16 hh = (bf16)hn;
        *(bf16*)(hbAB + boff) = hh;
        *(bf16*)(hbAB + 8192 + boff) = (bf16)(hn - (float)hh);
        hn = hnB[r];
        hh = (bf16)hn;
        *(bf16*)(hbBB + boff) = hh;
        *(bf16*)(hbBB + 8192 + boff) = (bf16)(hn - (float)hh);
      }
      // LN scalars for next step (own LDS partials + 12 remote partials)
      if (tid < 32) {
        int sidx = tid >> 4, row = tid & 15;
        float2 (*spwX)[16] = sidx ? spwB : spwA;
        float su = 0.f, qu = 0.f;
#pragma unroll
        for (int wv = 0; wv < 4; ++wv) {
          float2 p2 = spwX[wv][row];
          su += p2.x;
          qu += p2.y;
        }
        u64 lv[12];
#pragma unroll
        for (int pi = 0; pi < 3; ++pi) {
          int qq = (q + 1 + pi) & 3;
          int pbid = qq * 4 + gpair;
          const u64* ps = pub_s + ((size_t)(slot * 16 + pbid) * 2 + sidx) * 64;
#pragma unroll
          for (int wv = 0; wv < 4; ++wv)
            lv[pi * 4 + wv] = __hip_atomic_load(&ps[wv * 16 + row], __ATOMIC_RELAXED,
                                                __HIP_MEMORY_SCOPE_AGENT);
        }
#pragma unroll
        for (int i = 0; i < 12; ++i) {
          su += __builtin_bit_cast(float, (u32)(lv[i] & 0xffffffffu));
          qu += __builtin_bit_cast(float, (u32)(lv[i] >> 32));
        }
        float mu = su * (1.f / 256.f);
        float var = qu * (1.f / 256.f) - mu * mu;
        float rs = rsqrtf(var + EPSF);
        float (*mursX)[2] = sidx ? mursB : mursA;
        mursX[row][0] = mu * rs;
        mursX[row][1] = rs;
      }
    }
    __syncthreads();  // SYNC_D: hb + murs ready for next iteration
  }
}

// ---------------- host ----------------
extern "C" void kernel_launch(void* const* d_in, const int* in_sizes, int n_in,
                              void* d_out, int out_size, void* d_ws, size_t ws_size,
                              hipStream_t stream) {
  (void)in_sizes; (void)n_in; (void)out_size;
  const float* x = (const float*)d_in[0];
  const int* mask = (const int*)d_in[1];
  const float* Wih = (const float*)d_in[2];
  const float* Whh = (const float*)d_in[3];
  const float* bih = (const float*)d_in[4];
  const float* bhh = (const float*)d_in[5];
  const float* gamma = (const float*)d_in[6];
  const float* beta = (const float*)d_in[7];
  float* outp = (float*)d_out;
  char* ws = (char*)d_ws;

  const size_t extra = 4 * (512u << 10) + (8u << 10) + 3 * (128u << 10) +
                       (256u << 10) + (32u << 10) + (64u << 10);
  int Tc = 128;
  if (ws_size >= (size_t)1024 * 524288 + extra) Tc = 1024;
  else if (ws_size >= (size_t)512 * 524288 + extra) Tc = 512;
  else if (ws_size >= (size_t)256 * 524288 + extra) Tc = 256;

  size_t o = 0;
  auto take = [&](size_t bytes) { size_t r = o; o += (bytes + 255) & ~(size_t)255; return r; };
  size_t xw_off = take((size_t)Bb * Tc * G4v * 4);
  size_t wihh_off = take(512u << 10);
  size_t wihl_off = take(512u << 10);
  size_t whhh_off = take(512u << 10);
  size_t whhl_off = take(512u << 10);
  size_t rd_off = take(8u << 10);
  size_t sth_off = take(128u << 10);
  size_t stc_off = take(128u << 10);
  size_t sto_off = take(128u << 10);
  size_t pub_off = take(256u << 10);
  size_t pubs_off = take(32u << 10);
  size_t flg_off = take(256);

  bf16* wihh = (bf16*)(ws + wihh_off);
  bf16* wihl = (bf16*)(ws + wihl_off);
  bf16* whhh = (bf16*)(ws + whhh_off);
  bf16* whhl = (bf16*)(ws + whhl_off);
  float* rd = (float*)(ws + rd_off);
  float* xwp = (float*)(ws + xw_off);
  float* sth = (float*)(ws + sth_off);
  float* stc = (float*)(ws + stc_off);
  float* sto = (float*)(ws + sto_off);
  u32* pubh = (u32*)(ws + pub_off);
  u64* pubs = (u64*)(ws + pubs_off);
  int* flg = (int*)(ws + flg_off);

  hipMemsetAsync(flg, 0, 256, stream);
  k_conv_wih<<<dim3(256), dim3(256), 0, stream>>>(Wih, wihh, wihl);
  k_prep_whh<<<dim3(128), dim3(256), 0, stream>>>(Whh, gamma, whhh, whhl);
  k_prep_rd<<<dim3(4), dim3(256), 0, stream>>>(Whh, gamma, beta, bih, bhh, rd);

  int nchunk = Ss / Tc;
  int ntb = Tc / 128;
  for (int ci = 0; ci < nchunk; ++ci) {
    int t0 = ci * Tc;
    k_gemm<<<dim3(8 * ntb * 128), dim3(256), 0, stream>>>(x, wihh, wihl, xwp, t0, Tc, ntb);
    k_recur<<<dim3(16), dim3(256), 0, stream>>>(whhh, whhl, xwp, mask, rd, sth, stc, sto,
                                                pubh, pubs, flg, outp, t0, Tc,
                                                ci == 0 ? 1 : 0, ci == nchunk - 1 ? 1 : 0);
  }
}

// Round 6
// 4768.629 us; speedup vs baseline: 1.8359x; 1.8359x over previous
//
#include <hip/hip_runtime.h>
#include <hip/hip_bf16.h>
#include <stdint.h>

// ContainedLSTM: B=128, S=1024, I=256, H=256.
// Split-precision (Ootomo 2-term bf16) matmuls; LN folded into scalars.
// Recurrence: 32 WGs = 8 batch-groups x 4 j-quarters, W parked in AGPRs.
// Inter-WG h-exchange via SELF-VALIDATING tagged u64 atomics:
//   each published value = (step_tag<<32)|(bf16_hi<<16)|bf16_lo.
// Readers poll the data directly (batched retry) -- no flag, no ordering
// drain, no stats publish (remote LN partials recomputed from gathered h).
// 2 barriers/step. R4/R5 evidence: ~4 dependent Infinity-Cache round trips
// per step (agent scope bypasses non-coherent per-XCD L2) were the cost.

#define Bb 128
#define Ss 1024
#define Ii 256
#define Hh 256
#define G4v 1024
#define EPSF 1e-5f

typedef __bf16 bf16;
typedef __attribute__((ext_vector_type(8))) __bf16 bf16x8;
typedef __attribute__((ext_vector_type(4))) __bf16 bf16x4;
typedef __attribute__((ext_vector_type(4))) float f32x4;
typedef unsigned int u32;
typedef unsigned long long u64;

static __device__ __forceinline__ f32x4 mfma16(bf16x8 a, bf16x8 b, f32x4 c) {
  return __builtin_amdgcn_mfma_f32_16x16x32_bf16(a, b, c, 0, 0, 0);
}
static __device__ __forceinline__ float sigm(float x) { return 1.0f / (1.0f + __expf(-x)); }
static __device__ __forceinline__ float tanhf_(float x) {
  float e = __expf(-2.0f * fabsf(x));
  float t = (1.0f - e) / (1.0f + e);
  return x < 0.0f ? -t : t;
}
static __device__ __forceinline__ bf16 bfu(unsigned short u) {
  return __builtin_bit_cast(bf16, u);
}
static __device__ __forceinline__ unsigned short ubf(bf16 b) {
  return __builtin_bit_cast(unsigned short, b);
}

// ---------------- prep kernels ----------------
__global__ void k_conv_wih(const float* __restrict__ W, bf16* __restrict__ hi,
                           bf16* __restrict__ lo) {
  int i = (blockIdx.x * 256 + threadIdx.x) * 4;
  f32x4 v = *(const f32x4*)(W + i);
  bf16x4 h_, l_;
#pragma unroll
  for (int j = 0; j < 4; ++j) {
    bf16 hh = (bf16)v[j];
    h_[j] = hh;
    l_[j] = (bf16)(v[j] - (float)hh);
  }
  *(bf16x4*)(hi + i) = h_;
  *(bf16x4*)(lo + i) = l_;
}

// Wtil = W_hh * gamma, fragment-linear: Wf[(ntg*8+kt)*64 + lane][8] holds
// B-frag elem: Wtil[g = ntg*16 + (lane&15)][k = kt*32 + (lane>>4)*8 + j]
__global__ void k_prep_whh(const float* __restrict__ W, const float* __restrict__ gamma,
                           bf16* __restrict__ Whi, bf16* __restrict__ Wlo) {
  int tid = blockIdx.x * 256 + threadIdx.x;  // 0..32767
  int lane = tid & 63;
  int fk = tid >> 6;
  int ntg = fk >> 3, kt = fk & 7;
  int g = ntg * 16 + (lane & 15);
  int k = kt * 32 + ((lane >> 4) << 3);
  bf16x8 rh, rl;
#pragma unroll
  for (int j = 0; j < 8; ++j) {
    float wv = W[g * Hh + k + j] * gamma[k + j];
    bf16 hh = (bf16)wv;
    rh[j] = hh;
    rl[j] = (bf16)(wv - (float)hh);
  }
  *(bf16x8*)(Whi + (size_t)tid * 8) = rh;
  *(bf16x8*)(Wlo + (size_t)tid * 8) = rl;
}

__global__ void k_prep_rd(const float* __restrict__ W, const float* __restrict__ gamma,
                          const float* __restrict__ beta, const float* __restrict__ bih,
                          const float* __restrict__ bhh, float* __restrict__ RD) {
  int g = blockIdx.x * 256 + threadIdx.x;  // 1024 total
  float r = 0.f, d = 0.f;
  for (int k = 0; k < Hh; ++k) {
    float w = W[g * Hh + k];
    r += w * gamma[k];
    d += w * beta[k];
  }
  RD[2 * g] = r;
  RD[2 * g + 1] = d + bih[g] + bhh[g];
}

// ---------------- xw GEMM (split precision) ----------------
__global__ __launch_bounds__(256, 2) void k_gemm(const float* __restrict__ x,
                                                 const bf16* __restrict__ Whi,
                                                 const bf16* __restrict__ Wlo,
                                                 float* __restrict__ xw,
                                                 int t0, int Tc, int ntb) {
  __shared__ bf16 Bs[2][128 * 128];
  int bid = blockIdx.x;
  int b = bid & 127;
  int r2 = bid >> 7;
  int tb = r2 % ntb;
  int gt = r2 / ntb;
  int g0 = gt * 128;
  int tid = threadIdx.x, w = tid >> 6, lane = tid & 63;
  int li = lane & 15, lg = lane >> 4;
  char* BsB = (char*)Bs;
  int tbase = tb * 128 + 32 * w;
  f32x4 acc[2][8];
#pragma unroll
  for (int mt = 0; mt < 2; ++mt)
#pragma unroll
    for (int nt = 0; nt < 8; ++nt) acc[mt][nt] = (f32x4){0.f, 0.f, 0.f, 0.f};

  for (int kp = 0; kp < 2; ++kp) {
#pragma unroll
    for (int it = 0; it < 8; ++it) {
      int p = it * 4096 + tid * 16;
      int row = p >> 8, colb = p & 255;
      size_t goff = (size_t)(g0 + row) * 512 + kp * 256 + colb;
      int dst = row * 256 + (colb ^ ((row & 7) << 4));
      *(bf16x8*)(BsB + dst) = *(const bf16x8*)((const char*)Whi + goff);
      *(bf16x8*)(BsB + 32768 + dst) = *(const bf16x8*)((const char*)Wlo + goff);
    }
    __syncthreads();
#pragma unroll
    for (int kt = 0; kt < 4; ++kt) {
      int kl = kt * 32 + lg * 8;
      int kgl = kp * 128 + kl;
      bf16x8 ah[2], al[2];
#pragma unroll
      for (int mt = 0; mt < 2; ++mt) {
        int t = t0 + tbase + 16 * mt + li;
        const float* xp = x + ((size_t)b * Ss + t) * Ii + kgl;
        f32x4 f0 = *(const f32x4*)xp;
        f32x4 f1 = *(const f32x4*)(xp + 4);
        bf16x8 hv, lv;
#pragma unroll
        for (int j = 0; j < 4; ++j) {
          bf16 h0 = (bf16)f0[j];
          hv[j] = h0;
          lv[j] = (bf16)(f0[j] - (float)h0);
          bf16 h1 = (bf16)f1[j];
          hv[4 + j] = h1;
          lv[4 + j] = (bf16)(f1[j] - (float)h1);
        }
        ah[mt] = hv;
        al[mt] = lv;
      }
#pragma unroll
      for (int nt = 0; nt < 8; ++nt) {
        int grow = nt * 16 + li;
        int off = grow * 256 + ((kl * 2) ^ ((grow & 7) << 4));
        bf16x8 bh = *(const bf16x8*)(BsB + off);
        bf16x8 bl = *(const bf16x8*)(BsB + 32768 + off);
#pragma unroll
        for (int mt = 0; mt < 2; ++mt) {
          acc[mt][nt] = mfma16(ah[mt], bh, acc[mt][nt]);
          acc[mt][nt] = mfma16(ah[mt], bl, acc[mt][nt]);
          acc[mt][nt] = mfma16(al[mt], bh, acc[mt][nt]);
        }
      }
    }
    __syncthreads();
  }
#pragma unroll
  for (int mt = 0; mt < 2; ++mt)
#pragma unroll
    for (int nt = 0; nt < 8; ++nt)
#pragma unroll
      for (int r = 0; r < 4; ++r) {
        int tl = tbase + 16 * mt + lg * 4 + r;
        int g = g0 + nt * 16 + li;
        xw[((size_t)b * Tc + tl) * G4v + g] = acc[mt][nt][r];
      }
}

// ---------------- recurrence ----------------
// grid: 32 blocks, bid = q*8 + grp (partners of grp share bid%8 -> same XCD
// under round-robin dispatch); block 256 thr / 4 waves.
__global__ __launch_bounds__(256, 1) void k_recur(
    const bf16* __restrict__ Whi_f, const bf16* __restrict__ Wlo_f,
    const float* __restrict__ xw, const int* __restrict__ mask,
    const float* __restrict__ RD, float* __restrict__ st_h, float* __restrict__ st_c,
    float* __restrict__ st_o, u64* pub, float* __restrict__ out,
    int t0, int Tc, int first, int last) {
  __shared__ bf16 hb[2][16 * 256];   // h hi/lo planes, byte ^= (row&7)<<4 swizzle
  __shared__ float murs[2][16][2];   // (mu*rs, rs) per row, parity-buffered
  __shared__ float2 spw[4][16];      // per-wave per-row own-slice partials
  __shared__ float spart[16][16][2]; // init-path only
  int bid = blockIdx.x;
  int grp = bid & 7, q = bid >> 3;
  int tid = threadIdx.x, w = tid >> 6, lane = tid & 63;
  int li = lane & 15, lg = lane >> 4;
  int b0 = grp * 16;
  int jloc = (q * 4 + w) * 16 + li;
  char* hbB = (char*)hb;

  // park this wave's W-quarter (hi+lo) in AGPRs
  bf16x8 wph[4][8], wpl[4][8];
#pragma unroll
  for (int c = 0; c < 4; ++c)
#pragma unroll
    for (int kt = 0; kt < 8; ++kt) {
      int ntg = c * 16 + q * 4 + w;
      size_t off = ((size_t)(ntg * 8 + kt) * 64 + lane) * 8;
      wph[c][kt] = *(const bf16x8*)(Whi_f + off);
      wpl[c][kt] = *(const bf16x8*)(Wlo_f + off);
      asm volatile("" : "+a"(wph[c][kt]), "+a"(wpl[c][kt]));
    }
  float Rr[4], Dd[4];
#pragma unroll
  for (int c = 0; c < 4; ++c) {
    int g = c * 256 + jloc;
    Rr[c] = RD[2 * g];
    Dd[c] = RD[2 * g + 1];
  }

  float cst[4], ost[4];
  if (first) {
#pragma unroll
    for (int i = 0; i < 16; ++i) {
      hb[0][tid * 16 + i] = (bf16)0.0f;
      hb[1][tid * 16 + i] = (bf16)0.0f;
    }
#pragma unroll
    for (int r = 0; r < 4; ++r) { cst[r] = 0.f; ost[r] = 0.f; }
    if (tid < 16) { murs[0][tid][0] = 0.f; murs[0][tid][1] = rsqrtf(EPSF); }
  } else {
    int row = tid >> 4, cs = tid & 15, jseg = cs * 16;
    float s = 0.f, ss = 0.f;
#pragma unroll
    for (int i = 0; i < 16; ++i) {
      float v = st_h[(size_t)(b0 + row) * Hh + jseg + i];
      s += v;
      ss += v * v;
      bf16 hh = (bf16)v;
      int boff = row * 512 + (((jseg + i) * 2) ^ ((row & 7) << 4));
      *(bf16*)(hbB + boff) = hh;
      *(bf16*)(hbB + 8192 + boff) = (bf16)(v - (float)hh);
    }
    spart[row][cs][0] = s;
    spart[row][cs][1] = ss;
#pragma unroll
    for (int r = 0; r < 4; ++r) {
      int m = lg * 4 + r;
      cst[r] = st_c[(size_t)(b0 + m) * Hh + jloc];
      ost[r] = st_o[(size_t)(b0 + m) * Hh + jloc];
    }
    __syncthreads();
    if (tid < 16) {
      float s2 = 0.f, ss2 = 0.f;
#pragma unroll
      for (int i = 0; i < 16; ++i) { s2 += spart[tid][i][0]; ss2 += spart[tid][i][1]; }
      float mu = s2 * (1.f / 256.f);
      float var = ss2 * (1.f / 256.f) - mu * mu;
      float rs = rsqrtf(var + EPSF);
      murs[0][tid][0] = mu * rs;
      murs[0][tid][1] = rs;
    }
  }
  __syncthreads();

  // preload xw/mask for tl=0
  float xwv[4][4];
  int mk[4];
#pragma unroll
  for (int c = 0; c < 4; ++c)
#pragma unroll
    for (int r = 0; r < 4; ++r)
      xwv[c][r] = xw[((size_t)(b0 + lg * 4 + r) * Tc + 0) * G4v + c * 256 + jloc];
#pragma unroll
  for (int r = 0; r < 4; ++r) mk[r] = mask[(size_t)(b0 + lg * 4 + r) * Ss + t0];

  int grow = tid >> 4, gcg = tid & 15;  // gather role: row, col-group

  for (int tl = 0; tl < Tc; ++tl) {
    int tg = t0 + tl;
    int slot = (tg + 1) & 1;
    u32 want = (u32)(tg + 1);

    // P1: split MFMA  gates_acc = Wtil * h
    f32x4 acc[4];
#pragma unroll
    for (int c = 0; c < 4; ++c) acc[c] = (f32x4){0.f, 0.f, 0.f, 0.f};
#pragma unroll
    for (int kt = 0; kt < 8; ++kt) {
      int aoff = li * 512 + (((kt * 32 + lg * 8) * 2) ^ ((li & 7) << 4));
      bf16x8 ah = *(const bf16x8*)(hbB + aoff);
      bf16x8 al = *(const bf16x8*)(hbB + 8192 + aoff);
#pragma unroll
      for (int c = 0; c < 4; ++c) {
        acc[c] = mfma16(ah, wph[c][kt], acc[c]);
        acc[c] = mfma16(ah, wpl[c][kt], acc[c]);
        acc[c] = mfma16(al, wph[c][kt], acc[c]);
      }
    }
    float mrs[4], rsv[4];
#pragma unroll
    for (int r = 0; r < 4; ++r) {
      int m = lg * 4 + r;
      mrs[r] = murs[tl & 1][m][0];
      rsv[r] = murs[tl & 1][m][1];
    }
    __syncthreads();  // SYNC_A: all waves done reading hb (state t) + murs

    // P2: gates -> c,h,out; own hb slice; tagged publish (fire-and-forget)
    float hnew[4];
#pragma unroll
    for (int r = 0; r < 4; ++r) {
      float i_ = acc[0][r] * rsv[r] - mrs[r] * Rr[0] + Dd[0] + xwv[0][r];
      float f_ = acc[1][r] * rsv[r] - mrs[r] * Rr[1] + Dd[1] + xwv[1][r];
      float g_ = acc[2][r] * rsv[r] - mrs[r] * Rr[2] + Dd[2] + xwv[2][r];
      float o_ = acc[3][r] * rsv[r] - mrs[r] * Rr[3] + Dd[3] + xwv[3][r];
      float cn = sigm(f_) * cst[r] + sigm(i_) * tanhf_(g_);
      float hn = sigm(o_) * tanhf_(cn);
      cst[r] = cn;
      ost[r] = mk[r] ? ost[r] : hn;
      hnew[r] = hn;
    }
    u64* ph = pub + (size_t)(slot * 32 + bid) * 1024;
#pragma unroll
    for (int r = 0; r < 4; ++r) {
      int m = lg * 4 + r;
      float hn = hnew[r];
      bf16 hh = (bf16)hn;
      bf16 hl = (bf16)(hn - (float)hh);
      int boff = m * 512 + ((jloc * 2) ^ ((m & 7) << 4));
      *(bf16*)(hbB + boff) = hh;
      *(bf16*)(hbB + 8192 + boff) = hl;
      u64 pv = ((u64)want << 32) | ((u32)ubf(hh) << 16) | (u32)ubf(hl);
      __hip_atomic_store(&ph[m * 64 + (w * 16 + li)], pv, __ATOMIC_RELAXED,
                         __HIP_MEMORY_SCOPE_AGENT);
    }
    // own-slice LN partials (shfl over the 16 li lanes)
    {
      float sr[4], qr[4];
#pragma unroll
      for (int r = 0; r < 4; ++r) { sr[r] = hnew[r]; qr[r] = hnew[r] * hnew[r]; }
#pragma unroll
      for (int msk = 1; msk < 16; msk <<= 1)
#pragma unroll
        for (int r = 0; r < 4; ++r) {
          sr[r] += __shfl_xor(sr[r], msk);
          qr[r] += __shfl_xor(qr[r], msk);
        }
      if (li == 0)
#pragma unroll
        for (int r = 0; r < 4; ++r) spw[w][lg * 4 + r] = make_float2(sr[r], qr[r]);
    }
    if (tl == Tc - 1) {
#pragma unroll
      for (int r = 0; r < 4; ++r) {
        int m = lg * 4 + r;
        st_h[(size_t)(b0 + m) * Hh + jloc] = hnew[r];
        st_c[(size_t)(b0 + m) * Hh + jloc] = cst[r];
        st_o[(size_t)(b0 + m) * Hh + jloc] = ost[r];
      }
      if (last) {
#pragma unroll
        for (int r = 0; r < 4; ++r) out[(size_t)(b0 + lg * 4 + r) * Hh + jloc] = ost[r];
      }
    }
    // prefetch next xw/mask (overlaps the poll window)
    {
      int tln = (tl + 1 < Tc) ? tl + 1 : Tc - 1;
#pragma unroll
      for (int c = 0; c < 4; ++c)
#pragma unroll
        for (int r = 0; r < 4; ++r)
          xwv[c][r] = xw[((size_t)(b0 + lg * 4 + r) * Tc + tln) * G4v + c * 256 + jloc];
#pragma unroll
      for (int r = 0; r < 4; ++r) mk[r] = mask[(size_t)(b0 + lg * 4 + r) * Ss + t0 + tln];
    }

    // P3: gather partner slices, polling self-validating tags (batched retry)
    u64 gv[3][4];
    const u64* srcs[3];
#pragma unroll
    for (int pi = 0; pi < 3; ++pi) {
      int qq = (q + 1 + pi) & 3;
      int pbid = qq * 8 + grp;
      srcs[pi] = pub + (size_t)(slot * 32 + pbid) * 1024 + grow * 64 + gcg * 4;
#pragma unroll
      for (int e = 0; e < 4; ++e)
        gv[pi][e] = __hip_atomic_load(&srcs[pi][e], __ATOMIC_RELAXED,
                                      __HIP_MEMORY_SCOPE_AGENT);
    }
    {
      int cnt = 0;
      bool ok = false;
      while (!ok) {
        ok = true;
#pragma unroll
        for (int pi = 0; pi < 3; ++pi)
#pragma unroll
          for (int e = 0; e < 4; ++e)
            if ((u32)(gv[pi][e] >> 32) != want) {
              ok = false;
              gv[pi][e] = __hip_atomic_load(&srcs[pi][e], __ATOMIC_RELAXED,
                                            __HIP_MEMORY_SCOPE_AGENT);
            }
        if (++cnt > (1 << 22)) break;  // hang insurance
      }
    }
    // unpack -> hb planes; accumulate remote LN partials in regs
    float su = 0.f, qu = 0.f;
#pragma unroll
    for (int pi = 0; pi < 3; ++pi) {
      int qq = (q + 1 + pi) & 3;
      int j0 = qq * 64 + gcg * 4;
      int boff = grow * 512 + ((j0 * 2) ^ ((grow & 7) << 4));
      bf16x4 h4, l4;
#pragma unroll
      for (int e = 0; e < 4; ++e) {
        u32 d = (u32)gv[pi][e];
        bf16 hh = bfu((unsigned short)(d >> 16));
        bf16 hl = bfu((unsigned short)(d & 0xffffu));
        h4[e] = hh;
        l4[e] = hl;
        float f = (float)hh + (float)hl;
        su += f;
        qu += f * f;
      }
      *(bf16x4*)(hbB + boff) = h4;
      *(bf16x4*)(hbB + 8192 + boff) = l4;
    }
    // reduce remote partials across the 16 col-group lanes of this row
#pragma unroll
    for (int msk = 1; msk < 16; msk <<= 1) {
      su += __shfl_xor(su, msk);
      qu += __shfl_xor(qu, msk);
    }
    __syncthreads();  // SYNC_D: hb complete; spw (all waves) visible
    if (li == 0) {
      float s = su + spw[0][grow].x + spw[1][grow].x + spw[2][grow].x + spw[3][grow].x;
      float ss2 = qu + spw[0][grow].y + spw[1][grow].y + spw[2][grow].y + spw[3][grow].y;
      float mu = s * (1.f / 256.f);
      float var = ss2 * (1.f / 256.f) - mu * mu;
      float rs = rsqrtf(var + EPSF);
      murs[(tl + 1) & 1][grow][0] = mu * rs;
      murs[(tl + 1) & 1][grow][1] = rs;
    }
    // murs consumed after next SYNC_A -> no extra barrier needed
  }
}

// ---------------- host ----------------
extern "C" void kernel_launch(void* const* d_in, const int* in_sizes, int n_in,
                              void* d_out, int out_size, void* d_ws, size_t ws_size,
                              hipStream_t stream) {
  (void)in_sizes; (void)n_in; (void)out_size;
  const float* x = (const float*)d_in[0];
  const int* mask = (const int*)d_in[1];
  const float* Wih = (const float*)d_in[2];
  const float* Whh = (const float*)d_in[3];
  const float* bih = (const float*)d_in[4];
  const float* bhh = (const float*)d_in[5];
  const float* gamma = (const float*)d_in[6];
  const float* beta = (const float*)d_in[7];
  float* outp = (float*)d_out;
  char* ws = (char*)d_ws;

  const size_t extra = 4 * (512u << 10) + (8u << 10) + 3 * (128u << 10) +
                       (512u << 10) + (64u << 10);
  int Tc = 128;
  if (ws_size >= (size_t)1024 * 524288 + extra) Tc = 1024;
  else if (ws_size >= (size_t)512 * 524288 + extra) Tc = 512;
  else if (ws_size >= (size_t)256 * 524288 + extra) Tc = 256;

  size_t o = 0;
  auto take = [&](size_t bytes) { size_t r = o; o += (bytes + 255) & ~(size_t)255; return r; };
  size_t xw_off = take((size_t)Bb * Tc * G4v * 4);
  size_t wihh_off = take(512u << 10);
  size_t wihl_off = take(512u << 10);
  size_t whhh_off = take(512u << 10);
  size_t whhl_off = take(512u << 10);
  size_t rd_off = take(8u << 10);
  size_t sth_off = take(128u << 10);
  size_t stc_off = take(128u << 10);
  size_t sto_off = take(128u << 10);
  size_t pub_off = take(512u << 10);

  bf16* wihh = (bf16*)(ws + wihh_off);
  bf16* wihl = (bf16*)(ws + wihl_off);
  bf16* whhh = (bf16*)(ws + whhh_off);
  bf16* whhl = (bf16*)(ws + whhl_off);
  float* rd = (float*)(ws + rd_off);
  float* xwp = (float*)(ws + xw_off);
  float* sth = (float*)(ws + sth_off);
  float* stc = (float*)(ws + stc_off);
  float* sto = (float*)(ws + sto_off);
  u64* pubh = (u64*)(ws + pub_off);

  // clear pub tags (tag 0 < any step tag) -- removes all staleness hazards
  hipMemsetAsync(pubh, 0, 512u << 10, stream);
  k_conv_wih<<<dim3(256), dim3(256), 0, stream>>>(Wih, wihh, wihl);
  k_prep_whh<<<dim3(128), dim3(256), 0, stream>>>(Whh, gamma, whhh, whhl);
  k_prep_rd<<<dim3(4), dim3(256), 0, stream>>>(Whh, gamma, beta, bih, bhh, rd);

  int nchunk = Ss / Tc;
  int ntb = Tc / 128;
  for (int ci = 0; ci < nchunk; ++ci) {
    int t0 = ci * Tc;
    k_gemm<<<dim3(8 * ntb * 128), dim3(256), 0, stream>>>(x, wihh, wihl, xwp, t0, Tc, ntb);
    k_recur<<<dim3(32), dim3(256), 0, stream>>>(whhh, whhl, xwp, mask, rd, sth, stc, sto,
                                                pubh, outp, t0, Tc,
                                                ci == 0 ? 1 : 0, ci == nchunk - 1 ? 1 : 0);
  }
}

// Round 7
// 4756.540 us; speedup vs baseline: 1.8405x; 1.0025x over previous
//
#include <hip/hip_runtime.h>
#include <hip/hip_bf16.h>
#include <stdint.h>

// ContainedLSTM: B=128, S=1024, I=256, H=256.
// xw = x@W_ih^T: split-bf16 (Ootomo) MFMA GEMM -> fp32-grade, chunked in ws.
// Recurrence: 32 WGs = 8 batch-groups x 4 j-quarters.
//   W_hh*gamma parked in AGPRs as SINGLE-PLANE f16 (2^-11 mantissa, error
//   budget ~2e-3 final vs 1.65e-2 threshold); h carried as f16 hi+lo planes
//   -> 64 MFMAs/step in two 8-deep chains per gate.
// Inter-WG h-exchange: self-validating tagged u64 (tag<<32 | f16hi<<16|f16lo),
// BATCH-SWEEP poll: every sweep reloads ALL 12 words unconditionally (no
// divergent per-element retry -- R6's serialized masked reloads were ~12
// dependent IF-cache latencies ~ the whole 3us/step wait).

#define Bb 128
#define Ss 1024
#define Ii 256
#define Hh 256
#define G4v 1024
#define EPSF 1e-5f

typedef __bf16 bf16;
typedef _Float16 f16;
typedef __attribute__((ext_vector_type(8))) __bf16 bf16x8;
typedef __attribute__((ext_vector_type(4))) __bf16 bf16x4;
typedef __attribute__((ext_vector_type(8))) _Float16 f16x8;
typedef __attribute__((ext_vector_type(4))) _Float16 f16x4;
typedef __attribute__((ext_vector_type(4))) float f32x4;
typedef unsigned int u32;
typedef unsigned long long u64;

static __device__ __forceinline__ f32x4 mfma16b(bf16x8 a, bf16x8 b, f32x4 c) {
  return __builtin_amdgcn_mfma_f32_16x16x32_bf16(a, b, c, 0, 0, 0);
}
static __device__ __forceinline__ f32x4 mfma16h(f16x8 a, f16x8 b, f32x4 c) {
  return __builtin_amdgcn_mfma_f32_16x16x32_f16(a, b, c, 0, 0, 0);
}
static __device__ __forceinline__ float sigm(float x) { return 1.0f / (1.0f + __expf(-x)); }
static __device__ __forceinline__ float tanhf_(float x) {
  float e = __expf(-2.0f * fabsf(x));
  float t = (1.0f - e) / (1.0f + e);
  return x < 0.0f ? -t : t;
}
static __device__ __forceinline__ unsigned short ush(f16 h) {
  return __builtin_bit_cast(unsigned short, h);
}
static __device__ __forceinline__ f16 hus(unsigned short u) {
  return __builtin_bit_cast(f16, u);
}

// ---------------- prep kernels ----------------
__global__ void k_conv_wih(const float* __restrict__ W, bf16* __restrict__ hi,
                           bf16* __restrict__ lo) {
  int i = (blockIdx.x * 256 + threadIdx.x) * 4;
  f32x4 v = *(const f32x4*)(W + i);
  bf16x4 h_, l_;
#pragma unroll
  for (int j = 0; j < 4; ++j) {
    bf16 hh = (bf16)v[j];
    h_[j] = hh;
    l_[j] = (bf16)(v[j] - (float)hh);
  }
  *(bf16x4*)(hi + i) = h_;
  *(bf16x4*)(lo + i) = l_;
}

// Wtil = W_hh * gamma -> single f16 plane, fragment-linear:
// Wf[(ntg*8+kt)*64 + lane][8] = Wtil[g=ntg*16+(lane&15)][k=kt*32+(lane>>4)*8+j]
__global__ void k_prep_whh(const float* __restrict__ W, const float* __restrict__ gamma,
                           f16* __restrict__ Wf) {
  int tid = blockIdx.x * 256 + threadIdx.x;  // 0..32767
  int lane = tid & 63;
  int fk = tid >> 6;
  int ntg = fk >> 3, kt = fk & 7;
  int g = ntg * 16 + (lane & 15);
  int k = kt * 32 + ((lane >> 4) << 3);
  f16x8 r;
#pragma unroll
  for (int j = 0; j < 8; ++j) r[j] = (f16)(W[g * Hh + k + j] * gamma[k + j]);
  *(f16x8*)(Wf + (size_t)tid * 8) = r;
}

__global__ void k_prep_rd(const float* __restrict__ W, const float* __restrict__ gamma,
                          const float* __restrict__ beta, const float* __restrict__ bih,
                          const float* __restrict__ bhh, float* __restrict__ RD) {
  int g = blockIdx.x * 256 + threadIdx.x;  // 1024 total
  float r = 0.f, d = 0.f;
  for (int k = 0; k < Hh; ++k) {
    float w = W[g * Hh + k];
    r += w * gamma[k];
    d += w * beta[k];
  }
  RD[2 * g] = r;
  RD[2 * g + 1] = d + bih[g] + bhh[g];
}

// ---------------- xw GEMM (split-bf16, unchanged) ----------------
__global__ __launch_bounds__(256, 2) void k_gemm(const float* __restrict__ x,
                                                 const bf16* __restrict__ Whi,
                                                 const bf16* __restrict__ Wlo,
                                                 float* __restrict__ xw,
                                                 int t0, int Tc, int ntb) {
  __shared__ bf16 Bs[2][128 * 128];
  int bid = blockIdx.x;
  int b = bid & 127;
  int r2 = bid >> 7;
  int tb = r2 % ntb;
  int gt = r2 / ntb;
  int g0 = gt * 128;
  int tid = threadIdx.x, w = tid >> 6, lane = tid & 63;
  int li = lane & 15, lg = lane >> 4;
  char* BsB = (char*)Bs;
  int tbase = tb * 128 + 32 * w;
  f32x4 acc[2][8];
#pragma unroll
  for (int mt = 0; mt < 2; ++mt)
#pragma unroll
    for (int nt = 0; nt < 8; ++nt) acc[mt][nt] = (f32x4){0.f, 0.f, 0.f, 0.f};

  for (int kp = 0; kp < 2; ++kp) {
#pragma unroll
    for (int it = 0; it < 8; ++it) {
      int p = it * 4096 + tid * 16;
      int row = p >> 8, colb = p & 255;
      size_t goff = (size_t)(g0 + row) * 512 + kp * 256 + colb;
      int dst = row * 256 + (colb ^ ((row & 7) << 4));
      *(bf16x8*)(BsB + dst) = *(const bf16x8*)((const char*)Whi + goff);
      *(bf16x8*)(BsB + 32768 + dst) = *(const bf16x8*)((const char*)Wlo + goff);
    }
    __syncthreads();
#pragma unroll
    for (int kt = 0; kt < 4; ++kt) {
      int kl = kt * 32 + lg * 8;
      int kgl = kp * 128 + kl;
      bf16x8 ah[2], al[2];
#pragma unroll
      for (int mt = 0; mt < 2; ++mt) {
        int t = t0 + tbase + 16 * mt + li;
        const float* xp = x + ((size_t)b * Ss + t) * Ii + kgl;
        f32x4 f0 = *(const f32x4*)xp;
        f32x4 f1 = *(const f32x4*)(xp + 4);
        bf16x8 hv, lv;
#pragma unroll
        for (int j = 0; j < 4; ++j) {
          bf16 h0 = (bf16)f0[j];
          hv[j] = h0;
          lv[j] = (bf16)(f0[j] - (float)h0);
          bf16 h1 = (bf16)f1[j];
          hv[4 + j] = h1;
          lv[4 + j] = (bf16)(f1[j] - (float)h1);
        }
        ah[mt] = hv;
        al[mt] = lv;
      }
#pragma unroll
      for (int nt = 0; nt < 8; ++nt) {
        int grow = nt * 16 + li;
        int off = grow * 256 + ((kl * 2) ^ ((grow & 7) << 4));
        bf16x8 bh = *(const bf16x8*)(BsB + off);
        bf16x8 bl = *(const bf16x8*)(BsB + 32768 + off);
#pragma unroll
        for (int mt = 0; mt < 2; ++mt) {
          acc[mt][nt] = mfma16b(ah[mt], bh, acc[mt][nt]);
          acc[mt][nt] = mfma16b(ah[mt], bl, acc[mt][nt]);
          acc[mt][nt] = mfma16b(al[mt], bh, acc[mt][nt]);
        }
      }
    }
    __syncthreads();
  }
#pragma unroll
  for (int mt = 0; mt < 2; ++mt)
#pragma unroll
    for (int nt = 0; nt < 8; ++nt)
#pragma unroll
      for (int r = 0; r < 4; ++r) {
        int tl = tbase + 16 * mt + lg * 4 + r;
        int g = g0 + nt * 16 + li;
        xw[((size_t)b * Tc + tl) * G4v + g] = acc[mt][nt][r];
      }
}

// ---------------- recurrence ----------------
// grid: 32 blocks, bid = q*8 + grp; block 256 thr / 4 waves.
__global__ __launch_bounds__(256, 1) void k_recur(
    const f16* __restrict__ Wf, const float* __restrict__ xw,
    const int* __restrict__ mask, const float* __restrict__ RD,
    float* __restrict__ st_h, float* __restrict__ st_c, float* __restrict__ st_o,
    u64* pub, float* __restrict__ out, int t0, int Tc, int first, int last) {
  __shared__ f16 hb[2][16 * 256];    // h hi/lo planes, byte ^= (row&7)<<4 swizzle
  __shared__ float murs[2][16][2];   // (mu*rs, rs) per row, parity-buffered
  __shared__ float2 spw[4][16];      // per-wave per-row own-slice partials
  __shared__ float spart[16][16][2]; // init-path only
  int bid = blockIdx.x;
  int grp = bid & 7, q = bid >> 3;
  int tid = threadIdx.x, w = tid >> 6, lane = tid & 63;
  int li = lane & 15, lg = lane >> 4;
  int b0 = grp * 16;
  int jloc = (q * 4 + w) * 16 + li;
  char* hbB = (char*)hb;

  // park this wave's W-quarter (single f16 plane, 128 regs) in AGPRs
  f16x8 wp[4][8];
#pragma unroll
  for (int c = 0; c < 4; ++c)
#pragma unroll
    for (int kt = 0; kt < 8; ++kt) {
      int ntg = c * 16 + q * 4 + w;
      wp[c][kt] = *(const f16x8*)(Wf + ((size_t)(ntg * 8 + kt) * 64 + lane) * 8);
      asm volatile("" : "+a"(wp[c][kt]));
    }
  float Rr[4], Dd[4];
#pragma unroll
  for (int c = 0; c < 4; ++c) {
    int g = c * 256 + jloc;
    Rr[c] = RD[2 * g];
    Dd[c] = RD[2 * g + 1];
  }

  float cst[4], ost[4];
  if (first) {
#pragma unroll
    for (int i = 0; i < 16; ++i) {
      hb[0][tid * 16 + i] = (f16)0.0f;
      hb[1][tid * 16 + i] = (f16)0.0f;
    }
#pragma unroll
    for (int r = 0; r < 4; ++r) { cst[r] = 0.f; ost[r] = 0.f; }
    if (tid < 16) { murs[0][tid][0] = 0.f; murs[0][tid][1] = rsqrtf(EPSF); }
  } else {
    int row = tid >> 4, cs = tid & 15, jseg = cs * 16;
    float s = 0.f, ss = 0.f;
#pragma unroll
    for (int i = 0; i < 16; ++i) {
      float v = st_h[(size_t)(b0 + row) * Hh + jseg + i];
      s += v;
      ss += v * v;
      f16 hh = (f16)v;
      int boff = row * 512 + (((jseg + i) * 2) ^ ((row & 7) << 4));
      *(f16*)(hbB + boff) = hh;
      *(f16*)(hbB + 8192 + boff) = (f16)(v - (float)hh);
    }
    spart[row][cs][0] = s;
    spart[row][cs][1] = ss;
#pragma unroll
    for (int r = 0; r < 4; ++r) {
      int m = lg * 4 + r;
      cst[r] = st_c[(size_t)(b0 + m) * Hh + jloc];
      ost[r] = st_o[(size_t)(b0 + m) * Hh + jloc];
    }
    __syncthreads();
    if (tid < 16) {
      float s2 = 0.f, ss2 = 0.f;
#pragma unroll
      for (int i = 0; i < 16; ++i) { s2 += spart[tid][i][0]; ss2 += spart[tid][i][1]; }
      float mu = s2 * (1.f / 256.f);
      float var = ss2 * (1.f / 256.f) - mu * mu;
      float rs = rsqrtf(var + EPSF);
      murs[0][tid][0] = mu * rs;
      murs[0][tid][1] = rs;
    }
  }
  __syncthreads();

  // preload xw/mask for tl=0
  float xwv[4][4];
  int mk[4];
#pragma unroll
  for (int c = 0; c < 4; ++c)
#pragma unroll
    for (int r = 0; r < 4; ++r)
      xwv[c][r] = xw[((size_t)(b0 + lg * 4 + r) * Tc + 0) * G4v + c * 256 + jloc];
#pragma unroll
  for (int r = 0; r < 4; ++r) mk[r] = mask[(size_t)(b0 + lg * 4 + r) * Ss + t0];

  int grow = tid >> 4, gcg = tid & 15;  // gather role: row, col-group

  for (int tl = 0; tl < Tc; ++tl) {
    int tg = t0 + tl;
    int slot = (tg + 1) & 1;
    u32 want = (u32)(tg + 1);

    // P1: two 8-deep MFMA chains per gate: (h_hi + h_lo) x W_f16
    f32x4 a0[4], a1[4];
#pragma unroll
    for (int c = 0; c < 4; ++c) {
      a0[c] = (f32x4){0.f, 0.f, 0.f, 0.f};
      a1[c] = (f32x4){0.f, 0.f, 0.f, 0.f};
    }
#pragma unroll
    for (int kt = 0; kt < 8; ++kt) {
      int aoff = li * 512 + (((kt * 32 + lg * 8) * 2) ^ ((li & 7) << 4));
      f16x8 ah = *(const f16x8*)(hbB + aoff);
      f16x8 al = *(const f16x8*)(hbB + 8192 + aoff);
#pragma unroll
      for (int c = 0; c < 4; ++c) {
        a0[c] = mfma16h(ah, wp[c][kt], a0[c]);
        a1[c] = mfma16h(al, wp[c][kt], a1[c]);
      }
    }
    float mrs[4], rsv[4];
#pragma unroll
    for (int r = 0; r < 4; ++r) {
      int m = lg * 4 + r;
      mrs[r] = murs[tl & 1][m][0];
      rsv[r] = murs[tl & 1][m][1];
    }
    __syncthreads();  // SYNC_A: all waves done reading hb (state t) + murs

    // P2: gates -> c,h,out; own hb slice; tagged publish
    float hnew[4];
#pragma unroll
    for (int r = 0; r < 4; ++r) {
      float i_ = (a0[0][r] + a1[0][r]) * rsv[r] - mrs[r] * Rr[0] + Dd[0] + xwv[0][r];
      float f_ = (a0[1][r] + a1[1][r]) * rsv[r] - mrs[r] * Rr[1] + Dd[1] + xwv[1][r];
      float g_ = (a0[2][r] + a1[2][r]) * rsv[r] - mrs[r] * Rr[2] + Dd[2] + xwv[2][r];
      float o_ = (a0[3][r] + a1[3][r]) * rsv[r] - mrs[r] * Rr[3] + Dd[3] + xwv[3][r];
      float cn = sigm(f_) * cst[r] + sigm(i_) * tanhf_(g_);
      float hn = sigm(o_) * tanhf_(cn);
      cst[r] = cn;
      ost[r] = mk[r] ? ost[r] : hn;
      hnew[r] = hn;
    }
    u64* ph = pub + (size_t)(slot * 32 + bid) * 1024;
#pragma unroll
    for (int r = 0; r < 4; ++r) {
      int m = lg * 4 + r;
      float hn = hnew[r];
      f16 hh = (f16)hn;
      f16 hl = (f16)(hn - (float)hh);
      int boff = m * 512 + ((jloc * 2) ^ ((m & 7) << 4));
      *(f16*)(hbB + boff) = hh;
      *(f16*)(hbB + 8192 + boff) = hl;
      u64 pv = ((u64)want << 32) | ((u32)ush(hh) << 16) | (u32)ush(hl);
      __hip_atomic_store(&ph[m * 64 + (w * 16 + li)], pv, __ATOMIC_RELAXED,
                         __HIP_MEMORY_SCOPE_AGENT);
    }

    // issue first gather sweep immediately (overlaps prefetch + stats below)
    u64 gv[3][4];
    const u64* srcs[3];
#pragma unroll
    for (int pi = 0; pi < 3; ++pi) {
      int qq = (q + 1 + pi) & 3;
      int pbid = qq * 8 + grp;
      srcs[pi] = pub + (size_t)(slot * 32 + pbid) * 1024 + grow * 64 + gcg * 4;
#pragma unroll
      for (int e = 0; e < 4; ++e)
        gv[pi][e] = __hip_atomic_load(&srcs[pi][e], __ATOMIC_RELAXED,
                                      __HIP_MEMORY_SCOPE_AGENT);
    }

    // own-slice LN partials (shfl over the 16 li lanes)
    {
      float sr[4], qr[4];
#pragma unroll
      for (int r = 0; r < 4; ++r) { sr[r] = hnew[r]; qr[r] = hnew[r] * hnew[r]; }
#pragma unroll
      for (int msk = 1; msk < 16; msk <<= 1)
#pragma unroll
        for (int r = 0; r < 4; ++r) {
          sr[r] += __shfl_xor(sr[r], msk);
          qr[r] += __shfl_xor(qr[r], msk);
        }
      if (li == 0)
#pragma unroll
        for (int r = 0; r < 4; ++r) spw[w][lg * 4 + r] = make_float2(sr[r], qr[r]);
    }
    if (tl == Tc - 1) {
#pragma unroll
      for (int r = 0; r < 4; ++r) {
        int m = lg * 4 + r;
        st_h[(size_t)(b0 + m) * Hh + jloc] = hnew[r];
        st_c[(size_t)(b0 + m) * Hh + jloc] = cst[r];
        st_o[(size_t)(b0 + m) * Hh + jloc] = ost[r];
      }
      if (last) {
#pragma unroll
        for (int r = 0; r < 4; ++r) out[(size_t)(b0 + lg * 4 + r) * Hh + jloc] = ost[r];
      }
    }
    // prefetch next xw/mask (overlaps the poll window)
    {
      int tln = (tl + 1 < Tc) ? tl + 1 : Tc - 1;
#pragma unroll
      for (int c = 0; c < 4; ++c)
#pragma unroll
        for (int r = 0; r < 4; ++r)
          xwv[c][r] = xw[((size_t)(b0 + lg * 4 + r) * Tc + tln) * G4v + c * 256 + jloc];
#pragma unroll
      for (int r = 0; r < 4; ++r) mk[r] = mask[(size_t)(b0 + lg * 4 + r) * Ss + t0 + tln];
    }

    // P3: BATCH-SWEEP poll: reload ALL 12 unconditionally until all tags fresh
    {
      u32 bad = 0;
#pragma unroll
      for (int pi = 0; pi < 3; ++pi)
#pragma unroll
        for (int e = 0; e < 4; ++e) bad |= (u32)(gv[pi][e] >> 32) ^ want;
      int cnt = 0;
      while (bad) {
#pragma unroll
        for (int pi = 0; pi < 3; ++pi)
#pragma unroll
          for (int e = 0; e < 4; ++e)
            gv[pi][e] = __hip_atomic_load(&srcs[pi][e], __ATOMIC_RELAXED,
                                          __HIP_MEMORY_SCOPE_AGENT);
        bad = 0;
#pragma unroll
        for (int pi = 0; pi < 3; ++pi)
#pragma unroll
          for (int e = 0; e < 4; ++e) bad |= (u32)(gv[pi][e] >> 32) ^ want;
        if (++cnt > (1 << 20)) break;  // hang insurance
      }
    }
    // unpack -> hb planes; accumulate remote LN partials in regs
    float su = 0.f, qu = 0.f;
#pragma unroll
    for (int pi = 0; pi < 3; ++pi) {
      int qq = (q + 1 + pi) & 3;
      int j0 = qq * 64 + gcg * 4;
      int boff = grow * 512 + ((j0 * 2) ^ ((grow & 7) << 4));
      f16x4 h4, l4;
#pragma unroll
      for (int e = 0; e < 4; ++e) {
        u32 d = (u32)gv[pi][e];
        f16 hh = hus((unsigned short)(d >> 16));
        f16 hl = hus((unsigned short)(d & 0xffffu));
        h4[e] = hh;
        l4[e] = hl;
        float f = (float)hh + (float)hl;
        su += f;
        qu += f * f;
      }
      *(f16x4*)(hbB + boff) = h4;
      *(f16x4*)(hbB + 8192 + boff) = l4;
    }
#pragma unroll
    for (int msk = 1; msk < 16; msk <<= 1) {
      su += __shfl_xor(su, msk);
      qu += __shfl_xor(qu, msk);
    }
    __syncthreads();  // SYNC_D: hb complete; spw (all waves) visible
    if (li == 0) {
      float s = su + spw[0][grow].x + spw[1][grow].x + spw[2][grow].x + spw[3][grow].x;
      float ss2 = qu + spw[0][grow].y + spw[1][grow].y + spw[2][grow].y + spw[3][grow].y;
      float mu = s * (1.f / 256.f);
      float var = ss2 * (1.f / 256.f) - mu * mu;
      float rs = rsqrtf(var + EPSF);
      murs[(tl + 1) & 1][grow][0] = mu * rs;
      murs[(tl + 1) & 1][grow][1] = rs;
    }
  }
}

// ---------------- host ----------------
extern "C" void kernel_launch(void* const* d_in, const int* in_sizes, int n_in,
                              void* d_out, int out_size, void* d_ws, size_t ws_size,
                              hipStream_t stream) {
  (void)in_sizes; (void)n_in; (void)out_size;
  const float* x = (const float*)d_in[0];
  const int* mask = (const int*)d_in[1];
  const float* Wih = (const float*)d_in[2];
  const float* Whh = (const float*)d_in[3];
  const float* bih = (const float*)d_in[4];
  const float* bhh = (const float*)d_in[5];
  const float* gamma = (const float*)d_in[6];
  const float* beta = (const float*)d_in[7];
  float* outp = (float*)d_out;
  char* ws = (char*)d_ws;

  const size_t extra = 3 * (512u << 10) + (8u << 10) + 3 * (128u << 10) +
                       (512u << 10) + (64u << 10);
  int Tc = 128;
  if (ws_size >= (size_t)1024 * 524288 + extra) Tc = 1024;
  else if (ws_size >= (size_t)512 * 524288 + extra) Tc = 512;
  else if (ws_size >= (size_t)256 * 524288 + extra) Tc = 256;

  size_t o = 0;
  auto take = [&](size_t bytes) { size_t r = o; o += (bytes + 255) & ~(size_t)255; return r; };
  size_t xw_off = take((size_t)Bb * Tc * G4v * 4);
  size_t wihh_off = take(512u << 10);
  size_t wihl_off = take(512u << 10);
  size_t whh_off = take(512u << 10);
  size_t rd_off = take(8u << 10);
  size_t sth_off = take(128u << 10);
  size_t stc_off = take(128u << 10);
  size_t sto_off = take(128u << 10);
  size_t pub_off = take(512u << 10);

  bf16* wihh = (bf16*)(ws + wihh_off);
  bf16* wihl = (bf16*)(ws + wihl_off);
  f16* whhf = (f16*)(ws + whh_off);
  float* rd = (float*)(ws + rd_off);
  float* xwp = (float*)(ws + xw_off);
  float* sth = (float*)(ws + sth_off);
  float* stc = (float*)(ws + stc_off);
  float* sto = (float*)(ws + sto_off);
  u64* pubh = (u64*)(ws + pub_off);

  // clear pub tags (tag 0 < any step tag) -- removes all staleness hazards
  hipMemsetAsync(pubh, 0, 512u << 10, stream);
  k_conv_wih<<<dim3(256), dim3(256), 0, stream>>>(Wih, wihh, wihl);
  k_prep_whh<<<dim3(128), dim3(256), 0, stream>>>(Whh, gamma, whhf);
  k_prep_rd<<<dim3(4), dim3(256), 0, stream>>>(Whh, gamma, beta, bih, bhh, rd);

  int nchunk = Ss / Tc;
  int ntb = Tc / 128;
  for (int ci = 0; ci < nchunk; ++ci) {
    int t0 = ci * Tc;
    k_gemm<<<dim3(8 * ntb * 128), dim3(256), 0, stream>>>(x, wihh, wihl, xwp, t0, Tc, ntb);
    k_recur<<<dim3(32), dim3(256), 0, stream>>>(whhf, xwp, mask, rd, sth, stc, sto,
                                                pubh, outp, t0, Tc,
                                                ci == 0 ? 1 : 0, ci == nchunk - 1 ? 1 : 0);
  }
}